// Round 1
// baseline (1603.056 us; speedup 1.0000x reference)
//
#include <hip/hip_runtime.h>
#include <hip/hip_bf16.h>
#include <math.h>

#define NN 50000
#define EE 640000
#define DD 128
#define NREL 8
#define NCLS 16

__device__ __forceinline__ void atomadd(float* p, float v) {
  unsafeAtomicAdd(p, v);  // hw global_atomic_add_f32 on gfx950 (coarse-grained mem)
}

// cnt[r*NN + dst] = number of edges of relation r into dst (as float)
__global__ __launch_bounds__(256) void count_kernel(const int* __restrict__ ei,
                                                    const int* __restrict__ et,
                                                    float* __restrict__ cnt) {
  int t = blockIdx.x * 256 + threadIdx.x;
  if (t < EE) {
    int rel = et[t];
    int dst = ei[EE + t];
    atomadd(&cnt[rel * NN + dst], 1.0f);
  }
}

// C[50000 x 128] = op(A)[50000 x 128] @ B'[128 x 128]
// MODE 0: B' = B row-major 128x128 (W1[r]); no relu on A
// MODE 1: B'[k][j] = W2[j/16][k][j%16] (8 relations' 128x16 concatenated); relu(A)
template <int MODE>
__global__ __launch_bounds__(256) void gemm_kernel(const float* __restrict__ A,
                                                   const float* __restrict__ B,
                                                   float* __restrict__ C) {
  __shared__ float As[16][68];   // [BK][BM+4] transposed; stride 272B keeps 16B align
  __shared__ float Bs[16][128];
  const int tid = threadIdx.x;
  const int m0 = blockIdx.x * 64;
  const int tm = tid & 15;       // output row group (4 rows)
  const int tn = tid >> 4;       // output col group (8 cols)
  const int ar = tid >> 2;       // A-load row 0..63
  const int ak = (tid & 3) << 2; // A-load k offset 0,4,8,12
  float acc[4][8] = {};
  for (int k0 = 0; k0 < 128; k0 += 16) {
    float4 av = make_float4(0.f, 0.f, 0.f, 0.f);
    int arow = m0 + ar;
    if (arow < NN) av = *(const float4*)&A[arow * DD + k0 + ak];
    if (MODE == 1) {
      av.x = fmaxf(av.x, 0.f); av.y = fmaxf(av.y, 0.f);
      av.z = fmaxf(av.z, 0.f); av.w = fmaxf(av.w, 0.f);
    }
    float4 bv[2];
#pragma unroll
    for (int l = 0; l < 2; l++) {
      int p = tid + l * 256;       // 512 float4s in the 16x128 B tile
      int bk = p >> 5;
      int j4 = (p & 31) << 2;
      if (MODE == 0) {
        bv[l] = *(const float4*)&B[(k0 + bk) * DD + j4];
      } else {
        int r = j4 >> 4, c = j4 & 15;
        bv[l] = *(const float4*)&B[r * (DD * NCLS) + (k0 + bk) * NCLS + c];
      }
    }
    __syncthreads();  // previous tile's compute done before overwrite
    As[ak + 0][ar] = av.x;
    As[ak + 1][ar] = av.y;
    As[ak + 2][ar] = av.z;
    As[ak + 3][ar] = av.w;
#pragma unroll
    for (int l = 0; l < 2; l++) {
      int p = tid + l * 256;
      int bk = p >> 5;
      int j4 = (p & 31) << 2;
      *(float4*)&Bs[bk][j4] = bv[l];
    }
    __syncthreads();
#pragma unroll
    for (int kk = 0; kk < 16; kk++) {
      float4 a = *(const float4*)&As[kk][tm * 4];
      float4 b0 = *(const float4*)&Bs[kk][tn * 8];
      float4 b1 = *(const float4*)&Bs[kk][tn * 8 + 4];
      float a_[4] = {a.x, a.y, a.z, a.w};
      float b_[8] = {b0.x, b0.y, b0.z, b0.w, b1.x, b1.y, b1.z, b1.w};
#pragma unroll
      for (int i = 0; i < 4; i++)
#pragma unroll
        for (int j = 0; j < 8; j++)
          acc[i][j] = fmaf(a_[i], b_[j], acc[i][j]);
    }
  }
#pragma unroll
  for (int i = 0; i < 4; i++) {
    int row = m0 + tm * 4 + i;
    if (row < NN) {
      *(float4*)&C[row * DD + tn * 8] =
          make_float4(acc[i][0], acc[i][1], acc[i][2], acc[i][3]);
      *(float4*)&C[row * DD + tn * 8 + 4] =
          make_float4(acc[i][4], acc[i][5], acc[i][6], acc[i][7]);
    }
  }
}

// layer-1 scatter for relation r: agg[dst][:] += (w/cnt) * H[src][:]
// 32 lanes per edge, float4 each
__global__ __launch_bounds__(256) void edge1_kernel(const int* __restrict__ ei,
                                                    const int* __restrict__ et,
                                                    const float* __restrict__ ew,
                                                    const float* __restrict__ cnt,
                                                    const float* __restrict__ H,
                                                    float* __restrict__ agg,
                                                    int r) {
  int t = blockIdx.x * 256 + threadIdx.x;
  int e = t >> 5;
  if (e >= EE) return;
  if (et[e] != r) return;
  int c4 = (t & 31) << 2;
  int src = ei[e];
  int dst = ei[EE + e];
  float scale = ew[e] / fmaxf(cnt[r * NN + dst], 1.0f);
  float4 h = *(const float4*)&H[src * DD + c4];
  atomadd(&agg[dst * DD + c4 + 0], scale * h.x);
  atomadd(&agg[dst * DD + c4 + 1], scale * h.y);
  atomadd(&agg[dst * DD + c4 + 2], scale * h.z);
  atomadd(&agg[dst * DD + c4 + 3], scale * h.w);
}

// layer-2 scatter, all relations in one pass; H2 holds [node][rel*16+c]
// 16 lanes per edge
__global__ __launch_bounds__(256) void edge2_kernel(const int* __restrict__ ei,
                                                    const int* __restrict__ et,
                                                    const float* __restrict__ ew,
                                                    const float* __restrict__ cnt,
                                                    const float* __restrict__ H2,
                                                    float* __restrict__ out) {
  int t = blockIdx.x * 256 + threadIdx.x;
  int e = t >> 4;
  if (e >= EE) return;
  int c = t & 15;
  int rel = et[e];
  int src = ei[e];
  int dst = ei[EE + e];
  float scale = ew[e] / fmaxf(cnt[rel * NN + dst], 1.0f);
  atomadd(&out[dst * NCLS + c], scale * H2[src * DD + rel * NCLS + c]);
}

__global__ __launch_bounds__(256) void lsm_kernel(float* __restrict__ out) {
  int t = blockIdx.x * 256 + threadIdx.x;
  if (t >= NN) return;
  float v[16];
#pragma unroll
  for (int i = 0; i < 4; i++) {
    float4 q = *(const float4*)&out[t * 16 + i * 4];
    v[i * 4 + 0] = q.x; v[i * 4 + 1] = q.y;
    v[i * 4 + 2] = q.z; v[i * 4 + 3] = q.w;
  }
  float m = v[0];
#pragma unroll
  for (int i = 1; i < 16; i++) m = fmaxf(m, v[i]);
  float s = 0.f;
#pragma unroll
  for (int i = 0; i < 16; i++) s += expf(v[i] - m);
  float l = m + logf(s);
#pragma unroll
  for (int i = 0; i < 4; i++) {
    *(float4*)&out[t * 16 + i * 4] =
        make_float4(v[i * 4 + 0] - l, v[i * 4 + 1] - l, v[i * 4 + 2] - l, v[i * 4 + 3] - l);
  }
}

extern "C" void kernel_launch(void* const* d_in, const int* in_sizes, int n_in,
                              void* d_out, int out_size, void* d_ws, size_t ws_size,
                              hipStream_t stream) {
  const float* x  = (const float*)d_in[0];
  const int*   ei = (const int*)d_in[1];   // [2*EE]: src then dst
  const int*   et = (const int*)d_in[2];   // [EE]
  const float* ew = (const float*)d_in[3]; // [EE]
  const float* W1 = (const float*)d_in[4]; // [8,128,128]
  const float* W2 = (const float*)d_in[5]; // [8,128,16]
  float* out = (float*)d_out;              // [NN,16]
  float* ws = (float*)d_ws;

  float* cnt  = ws;                        // NREL*NN      = 400000 floats
  float* agg1 = ws + 400000;               // NN*DD        = 6.4M floats
  float* H    = ws + 400000 + NN * DD;     // NN*DD        = 6.4M floats (reused layer 2)

  hipMemsetAsync(cnt, 0, (size_t)NREL * NN * sizeof(float), stream);
  hipMemsetAsync(agg1, 0, (size_t)NN * DD * sizeof(float), stream);
  hipMemsetAsync(out, 0, (size_t)NN * NCLS * sizeof(float), stream);

  count_kernel<<<(EE + 255) / 256, 256, 0, stream>>>(ei, et, cnt);

  const int gemm_grid = (NN + 63) / 64;  // 782
  for (int r = 0; r < NREL; r++) {
    gemm_kernel<0><<<gemm_grid, 256, 0, stream>>>(x, W1 + (size_t)r * DD * DD, H);
    edge1_kernel<<<(EE * 32) / 256, 256, 0, stream>>>(ei, et, ew, cnt, H, agg1, r);
  }

  // layer 2: one GEMM for all 8 relations (N = 8*16 = 128), relu fused on A-load
  gemm_kernel<1><<<gemm_grid, 256, 0, stream>>>(agg1, W2, H);
  edge2_kernel<<<(EE * 16) / 256, 256, 0, stream>>>(ei, et, ew, cnt, H, out);

  lsm_kernel<<<(NN + 255) / 256, 256, 0, stream>>>(out);
}

// Round 2
// 611.497 us; speedup vs baseline: 2.6215x; 2.6215x over previous
//
#include <hip/hip_runtime.h>
#include <hip/hip_bf16.h>
#include <math.h>

#define NN 50000
#define EE 640000
#define DD 128
#define NREL 8
#define NCLS 16
#define NBUCK (NREL * NN)          // 400000 (rel,dst) buckets
#define SCAN_NB ((NBUCK + 255) / 256)  // 1563
#define RGROUP 2                   // relations per H_all pass

__device__ __forceinline__ void atomaddf(float* p, float v) {
  unsafeAtomicAdd(p, v);  // hw global_atomic_add_f32
}

// ---------- CSR build ----------

// cnt[r*NN + dst] = edge count (float) per (rel,dst)
__global__ __launch_bounds__(256) void count_kernel(const int* __restrict__ ei,
                                                    const int* __restrict__ et,
                                                    float* __restrict__ cnt) {
  int t = blockIdx.x * 256 + threadIdx.x;
  if (t < EE) {
    int rel = et[t];
    int dst = ei[EE + t];
    atomaddf(&cnt[rel * NN + dst], 1.0f);
  }
}

// block-local exclusive scan of (int)cnt -> off, block totals -> bsum
__global__ __launch_bounds__(256) void scan1_kernel(const float* __restrict__ cnt,
                                                    int* __restrict__ off,
                                                    int* __restrict__ bsum) {
  __shared__ int s[256];
  const int tid = threadIdx.x;
  const int i = blockIdx.x * 256 + tid;
  int v = (i < NBUCK) ? (int)cnt[i] : 0;
  s[tid] = v;
  __syncthreads();
#pragma unroll
  for (int o = 1; o < 256; o <<= 1) {
    int t2 = (tid >= o) ? s[tid - o] : 0;
    __syncthreads();
    s[tid] += t2;
    __syncthreads();
  }
  if (i < NBUCK) off[i] = s[tid] - v;  // exclusive
  if (tid == 255) bsum[blockIdx.x] = s[255];
}

// single-block scan of the SCAN_NB block sums -> bpre (exclusive)
__global__ __launch_bounds__(256) void scan2_kernel(const int* __restrict__ bsum,
                                                    int* __restrict__ bpre) {
  __shared__ int s[256];
  __shared__ int carry;
  const int tid = threadIdx.x;
  if (tid == 0) carry = 0;
  __syncthreads();
  const int chunks = (SCAN_NB + 255) / 256;
  for (int c = 0; c < chunks; c++) {
    int idx = c * 256 + tid;
    int v = (idx < SCAN_NB) ? bsum[idx] : 0;
    s[tid] = v;
    __syncthreads();
#pragma unroll
    for (int o = 1; o < 256; o <<= 1) {
      int t2 = (tid >= o) ? s[tid - o] : 0;
      __syncthreads();
      s[tid] += t2;
      __syncthreads();
    }
    if (idx < SCAN_NB) bpre[idx] = carry + s[tid] - v;
    __syncthreads();
    if (tid == 255) carry += s[255];
    __syncthreads();
  }
}

__global__ __launch_bounds__(256) void scan3_kernel(int* __restrict__ off,
                                                    const int* __restrict__ bpre) {
  int i = blockIdx.x * 256 + threadIdx.x;
  if (i < NBUCK) off[i] += bpre[i >> 8];
  if (i == 0) off[NBUCK] = EE;
}

// place each edge into its (rel,dst) bucket; record = (src, w/max(cnt,1))
__global__ __launch_bounds__(256) void bucket_kernel(const int* __restrict__ ei,
                                                     const int* __restrict__ et,
                                                     const float* __restrict__ ew,
                                                     const float* __restrict__ cnt,
                                                     int* __restrict__ cursor,
                                                     uint2* __restrict__ rec) {
  int e = blockIdx.x * 256 + threadIdx.x;
  if (e >= EE) return;
  int rel = et[e];
  int dst = ei[EE + e];
  int src = ei[e];
  int key = rel * NN + dst;
  float scale = ew[e] / fmaxf(cnt[key], 1.0f);
  int pos = atomicAdd(&cursor[key], 1);
  rec[pos] = make_uint2((unsigned)src, __float_as_uint(scale));
}

// ---------- GEMMs (fp32 vector) ----------
// C[50000 x 128] = op(A) @ B'
// MODE 0: B' = W1[r] row-major 128x128; no relu
// MODE 1: B'[k][j] = W2[j/16][k][j%16]; relu(A)
template <int MODE>
__global__ __launch_bounds__(256) void gemm_kernel(const float* __restrict__ A,
                                                   const float* __restrict__ B,
                                                   float* __restrict__ C) {
  __shared__ float As[16][68];
  __shared__ float Bs[16][128];
  const int tid = threadIdx.x;
  const int m0 = blockIdx.x * 64;
  const int tm = tid & 15;
  const int tn = tid >> 4;
  const int ar = tid >> 2;
  const int ak = (tid & 3) << 2;
  float acc[4][8] = {};
  for (int k0 = 0; k0 < 128; k0 += 16) {
    float4 av = make_float4(0.f, 0.f, 0.f, 0.f);
    int arow = m0 + ar;
    if (arow < NN) av = *(const float4*)&A[arow * DD + k0 + ak];
    if (MODE == 1) {
      av.x = fmaxf(av.x, 0.f); av.y = fmaxf(av.y, 0.f);
      av.z = fmaxf(av.z, 0.f); av.w = fmaxf(av.w, 0.f);
    }
    float4 bv[2];
#pragma unroll
    for (int l = 0; l < 2; l++) {
      int p = tid + l * 256;
      int bk = p >> 5;
      int j4 = (p & 31) << 2;
      if (MODE == 0) {
        bv[l] = *(const float4*)&B[(k0 + bk) * DD + j4];
      } else {
        int r = j4 >> 4, c = j4 & 15;
        bv[l] = *(const float4*)&B[r * (DD * NCLS) + (k0 + bk) * NCLS + c];
      }
    }
    __syncthreads();
    As[ak + 0][ar] = av.x;
    As[ak + 1][ar] = av.y;
    As[ak + 2][ar] = av.z;
    As[ak + 3][ar] = av.w;
#pragma unroll
    for (int l = 0; l < 2; l++) {
      int p = tid + l * 256;
      int bk = p >> 5;
      int j4 = (p & 31) << 2;
      *(float4*)&Bs[bk][j4] = bv[l];
    }
    __syncthreads();
#pragma unroll
    for (int kk = 0; kk < 16; kk++) {
      float4 a = *(const float4*)&As[kk][tm * 4];
      float4 b0 = *(const float4*)&Bs[kk][tn * 8];
      float4 b1 = *(const float4*)&Bs[kk][tn * 8 + 4];
      float a_[4] = {a.x, a.y, a.z, a.w};
      float b_[8] = {b0.x, b0.y, b0.z, b0.w, b1.x, b1.y, b1.z, b1.w};
#pragma unroll
      for (int i = 0; i < 4; i++)
#pragma unroll
        for (int j = 0; j < 8; j++)
          acc[i][j] = fmaf(a_[i], b_[j], acc[i][j]);
    }
  }
#pragma unroll
  for (int i = 0; i < 4; i++) {
    int row = m0 + tm * 4 + i;
    if (row < NN) {
      *(float4*)&C[row * DD + tn * 8] =
          make_float4(acc[i][0], acc[i][1], acc[i][2], acc[i][3]);
      *(float4*)&C[row * DD + tn * 8 + 4] =
          make_float4(acc[i][4], acc[i][5], acc[i][6], acc[i][7]);
    }
  }
}

// ---------- gathers (no atomics) ----------

// layer-1: out1[v][c] (+)= sum over buckets (r0..r0+RGROUP-1, v) of scale*H[slot][src][c]
// 32 lanes per node, float4 per lane
__global__ __launch_bounds__(256) void gather1_kernel(const int* __restrict__ off,
                                                      const uint2* __restrict__ rec,
                                                      const float* __restrict__ Hall,
                                                      float* __restrict__ out1,
                                                      int r0, int first) {
  int t = blockIdx.x * 256 + threadIdx.x;
  int v = t >> 5;
  if (v >= NN) return;
  int c4 = (t & 31) << 2;
  float4 acc = make_float4(0.f, 0.f, 0.f, 0.f);
#pragma unroll
  for (int rr = 0; rr < RGROUP; rr++) {
    int b = (r0 + rr) * NN + v;
    int s = off[b], e = off[b + 1];
    const float* Hr = Hall + (size_t)rr * NN * DD;
    for (int i = s; i < e; i++) {
      uint2 q = rec[i];
      float sc = __uint_as_float(q.y);
      float4 h = *(const float4*)&Hr[(size_t)q.x * DD + c4];
      acc.x = fmaf(sc, h.x, acc.x);
      acc.y = fmaf(sc, h.y, acc.y);
      acc.z = fmaf(sc, h.z, acc.z);
      acc.w = fmaf(sc, h.w, acc.w);
    }
  }
  float* o = &out1[(size_t)v * DD + c4];
  if (first) {
    *(float4*)o = acc;
  } else {
    float4 p = *(const float4*)o;
    p.x += acc.x; p.y += acc.y; p.z += acc.z; p.w += acc.w;
    *(float4*)o = p;
  }
}

// layer-2: out[v][c] = sum_r sum over bucket (r,v) of scale*H2[src][r*16+c]
// 16 lanes per node
__global__ __launch_bounds__(256) void gather2_kernel(const int* __restrict__ off,
                                                      const uint2* __restrict__ rec,
                                                      const float* __restrict__ H2,
                                                      float* __restrict__ out) {
  int t = blockIdx.x * 256 + threadIdx.x;
  int v = t >> 4;
  if (v >= NN) return;
  int c = t & 15;
  float acc = 0.f;
#pragma unroll
  for (int r = 0; r < NREL; r++) {
    int b = r * NN + v;
    int s = off[b], e = off[b + 1];
    for (int i = s; i < e; i++) {
      uint2 q = rec[i];
      acc = fmaf(__uint_as_float(q.y), H2[(size_t)q.x * DD + r * NCLS + c], acc);
    }
  }
  out[(size_t)v * NCLS + c] = acc;
}

__global__ __launch_bounds__(256) void lsm_kernel(float* __restrict__ out) {
  int t = blockIdx.x * 256 + threadIdx.x;
  if (t >= NN) return;
  float v[16];
#pragma unroll
  for (int i = 0; i < 4; i++) {
    float4 q = *(const float4*)&out[t * 16 + i * 4];
    v[i * 4 + 0] = q.x; v[i * 4 + 1] = q.y;
    v[i * 4 + 2] = q.z; v[i * 4 + 3] = q.w;
  }
  float m = v[0];
#pragma unroll
  for (int i = 1; i < 16; i++) m = fmaxf(m, v[i]);
  float s = 0.f;
#pragma unroll
  for (int i = 0; i < 16; i++) s += expf(v[i] - m);
  float l = m + logf(s);
#pragma unroll
  for (int i = 0; i < 4; i++) {
    *(float4*)&out[t * 16 + i * 4] =
        make_float4(v[i * 4 + 0] - l, v[i * 4 + 1] - l, v[i * 4 + 2] - l, v[i * 4 + 3] - l);
  }
}

extern "C" void kernel_launch(void* const* d_in, const int* in_sizes, int n_in,
                              void* d_out, int out_size, void* d_ws, size_t ws_size,
                              hipStream_t stream) {
  const float* x  = (const float*)d_in[0];
  const int*   ei = (const int*)d_in[1];   // [2*EE]: src then dst
  const int*   et = (const int*)d_in[2];   // [EE]
  const float* ew = (const float*)d_in[3]; // [EE]
  const float* W1 = (const float*)d_in[4]; // [8,128,128]
  const float* W2 = (const float*)d_in[5]; // [8,128,16]
  float* out = (float*)d_out;              // [NN,16]
  float* ws = (float*)d_ws;

  // workspace layout (float offsets; ~86.7 MB total)
  float* cnt    = ws;                                  // 400000
  int*   off    = (int*)(ws + 400000);                 // 400001
  int*   bsum   = (int*)(ws + 800002);                 // 1563
  int*   bpre   = (int*)(ws + 801566);                 // 1563
  int*   cursor = (int*)(ws + 803130);                 // 400000
  uint2* rec    = (uint2*)(ws + 1203130);              // 640000 uint2 (8B-aligned: even float offset)
  float* H_all  = ws + 2483132;                        // RGROUP * 6.4M (16B-aligned: offset %4==0)
  float* out1   = H_all + (size_t)RGROUP * NN * DD;    // 6.4M

  hipMemsetAsync(cnt, 0, (size_t)NBUCK * sizeof(float), stream);

  count_kernel<<<(EE + 255) / 256, 256, 0, stream>>>(ei, et, cnt);
  scan1_kernel<<<SCAN_NB, 256, 0, stream>>>(cnt, off, bsum);
  scan2_kernel<<<1, 256, 0, stream>>>(bsum, bpre);
  scan3_kernel<<<SCAN_NB, 256, 0, stream>>>(off, bpre);
  hipMemcpyAsync(cursor, off, (size_t)NBUCK * sizeof(int), hipMemcpyDeviceToDevice, stream);
  bucket_kernel<<<(EE + 255) / 256, 256, 0, stream>>>(ei, et, ew, cnt, cursor, rec);

  const int gemm_grid = (NN + 63) / 64;  // 782
  const int g1_grid = (NN * 32) / 256;   // 6250
  for (int g = 0; g < NREL / RGROUP; g++) {
    int r0 = g * RGROUP;
    for (int rr = 0; rr < RGROUP; rr++) {
      gemm_kernel<0><<<gemm_grid, 256, 0, stream>>>(
          x, W1 + (size_t)(r0 + rr) * DD * DD, H_all + (size_t)rr * NN * DD);
    }
    gather1_kernel<<<g1_grid, 256, 0, stream>>>(off, rec, H_all, out1, r0, g == 0 ? 1 : 0);
  }

  // layer 2: one GEMM for all 8 relations (relu fused on A-load), H2 reuses H_all
  float* H2 = H_all;
  gemm_kernel<1><<<gemm_grid, 256, 0, stream>>>(out1, W2, H2);
  gather2_kernel<<<(NN * 16) / 256, 256, 0, stream>>>(off, rec, H2, out);

  lsm_kernel<<<(NN + 255) / 256, 256, 0, stream>>>(out);
}

// Round 3
// 345.305 us; speedup vs baseline: 4.6424x; 1.7709x over previous
//
#include <hip/hip_runtime.h>
#include <hip/hip_bf16.h>
#include <math.h>

#define NN 50000
#define EE 640000
#define DD 128
#define NREL 8
#define NCLS 16
#define NBUCK (NREL * NN)              // 400000 (rel,dst) buckets
#define SCAN_NB ((NBUCK + 255) / 256)  // 1563

typedef __attribute__((ext_vector_type(8))) short short8;   // 8 bf16 = 4 VGPRs
typedef __attribute__((ext_vector_type(4))) float f32x4;    // MFMA acc

__device__ __forceinline__ void atomaddf(float* p, float v) { unsafeAtomicAdd(p, v); }

__device__ __forceinline__ float bf2f(ushort u) {
  return __uint_as_float(((unsigned)u) << 16);
}
__device__ __forceinline__ ushort f2b(float f) {  // RNE
  unsigned u = __float_as_uint(f);
  u += 0x7fff + ((u >> 16) & 1);
  return (ushort)(u >> 16);
}

// ---------- CSR build ----------

__global__ __launch_bounds__(256) void count_kernel(const int* __restrict__ ei,
                                                    const int* __restrict__ et,
                                                    float* __restrict__ cnt) {
  int t = blockIdx.x * 256 + threadIdx.x;
  if (t < EE) {
    int rel = et[t];
    int dst = ei[EE + t];
    atomaddf(&cnt[rel * NN + dst], 1.0f);
  }
}

__global__ __launch_bounds__(256) void scan1_kernel(const float* __restrict__ cnt,
                                                    int* __restrict__ off,
                                                    int* __restrict__ bsum) {
  __shared__ int s[256];
  const int tid = threadIdx.x;
  const int i = blockIdx.x * 256 + tid;
  int v = (i < NBUCK) ? (int)cnt[i] : 0;
  s[tid] = v;
  __syncthreads();
#pragma unroll
  for (int o = 1; o < 256; o <<= 1) {
    int t2 = (tid >= o) ? s[tid - o] : 0;
    __syncthreads();
    s[tid] += t2;
    __syncthreads();
  }
  if (i < NBUCK) off[i] = s[tid] - v;
  if (tid == 255) bsum[blockIdx.x] = s[255];
}

__global__ __launch_bounds__(256) void scan2_kernel(const int* __restrict__ bsum,
                                                    int* __restrict__ bpre) {
  __shared__ int s[256];
  __shared__ int carry;
  const int tid = threadIdx.x;
  if (tid == 0) carry = 0;
  __syncthreads();
  const int chunks = (SCAN_NB + 255) / 256;
  for (int c = 0; c < chunks; c++) {
    int idx = c * 256 + tid;
    int v = (idx < SCAN_NB) ? bsum[idx] : 0;
    s[tid] = v;
    __syncthreads();
#pragma unroll
    for (int o = 1; o < 256; o <<= 1) {
      int t2 = (tid >= o) ? s[tid - o] : 0;
      __syncthreads();
      s[tid] += t2;
      __syncthreads();
    }
    if (idx < SCAN_NB) bpre[idx] = carry + s[tid] - v;
    __syncthreads();
    if (tid == 255) carry += s[255];
    __syncthreads();
  }
}

__global__ __launch_bounds__(256) void scan3_kernel(int* __restrict__ off,
                                                    const int* __restrict__ bpre) {
  int i = blockIdx.x * 256 + threadIdx.x;
  if (i < NBUCK) off[i] += bpre[i >> 8];
  if (i == 0) off[NBUCK] = EE;
}

__global__ __launch_bounds__(256) void bucket_kernel(const int* __restrict__ ei,
                                                     const int* __restrict__ et,
                                                     const float* __restrict__ ew,
                                                     const float* __restrict__ cnt,
                                                     int* __restrict__ cursor,
                                                     uint2* __restrict__ rec) {
  int e = blockIdx.x * 256 + threadIdx.x;
  if (e >= EE) return;
  int rel = et[e];
  int dst = ei[EE + e];
  int src = ei[e];
  int key = rel * NN + dst;
  float scale = ew[e] / fmaxf(cnt[key], 1.0f);
  int pos = atomicAdd(&cursor[key], 1);
  rec[pos] = make_uint2((unsigned)src, __float_as_uint(scale));
}

// ---------- packs ----------

__global__ __launch_bounds__(256) void pack_x_kernel(const float* __restrict__ x,
                                                     ushort* __restrict__ xb) {
  int t = blockIdx.x * 256 + threadIdx.x;  // NN*DD/4 threads
  if (t >= NN * DD / 4) return;
  float4 v = *(const float4*)&x[(size_t)t * 4];
  ushort4 o = make_ushort4(f2b(v.x), f2b(v.y), f2b(v.z), f2b(v.w));
  *(ushort4*)&xb[(size_t)t * 4] = o;
}

// W1T[r][n][k] = bf16(W1[r][k][n]); W2T[j][k] = bf16(W2[j>>4][k][j&15])
__global__ __launch_bounds__(256) void pack_w_kernel(const float* __restrict__ W1,
                                                     const float* __restrict__ W2,
                                                     ushort* __restrict__ W1T,
                                                     ushort* __restrict__ W2T) {
  int t = blockIdx.x * 256 + threadIdx.x;
  if (t < NREL * DD * DD) {
    int r = t >> 14, rem = t & 16383, n = rem >> 7, k = rem & 127;
    W1T[t] = f2b(W1[r * 16384 + k * 128 + n]);
  } else if (t < NREL * DD * DD + DD * DD) {
    int t2 = t - NREL * DD * DD;
    int j = t2 >> 7, k = t2 & 127;
    W2T[t2] = f2b(W2[(j >> 4) * (DD * NCLS) + k * NCLS + (j & 15)]);
  }
}

// ---------- bf16 MFMA GEMM: C[NN x 128](bf16) = A[NN x 128](bf16) @ Bt^T ----------
// Bt stored [n][k] (transposed weights). blockIdx.y selects relation slice.
__global__ __launch_bounds__(256) void mfma_gemm_kernel(const ushort* __restrict__ A,
                                                        const ushort* __restrict__ BtBase,
                                                        int btStride,
                                                        ushort* __restrict__ CBase,
                                                        long cStride) {
  __shared__ ushort As[128 * 136];
  __shared__ ushort Bs[128 * 136];
  const int tid = threadIdx.x;
  const int m0 = blockIdx.x * 128;
  const ushort* Bt = BtBase + (size_t)blockIdx.y * btStride;
  ushort* C = CBase + (size_t)blockIdx.y * cStride;

  // stage A (guarded) and Bt (full) tiles, 16B chunks
#pragma unroll
  for (int i = 0; i < 8; i++) {
    int seg = tid + i * 256;               // 2048 segments
    int row = seg >> 4, c8 = (seg & 15) * 8;
    uint4 va = make_uint4(0u, 0u, 0u, 0u);
    int gr = m0 + row;
    if (gr < NN) va = *(const uint4*)&A[(size_t)gr * DD + c8];
    *(uint4*)&As[row * 136 + c8] = va;
    uint4 vb = *(const uint4*)&Bt[row * DD + c8];
    *(uint4*)&Bs[row * 136 + c8] = vb;
  }
  __syncthreads();

  const int wave = tid >> 6, lane = tid & 63;
  const int lm = lane & 15, lkb = (lane >> 4) * 8;
  const int mbase = wave * 32;
  f32x4 acc[2][8];
#pragma unroll
  for (int t = 0; t < 2; t++)
#pragma unroll
    for (int n = 0; n < 8; n++) acc[t][n] = (f32x4){0.f, 0.f, 0.f, 0.f};

#pragma unroll
  for (int k0 = 0; k0 < 128; k0 += 32) {
    short8 a0 = *(const short8*)&As[(mbase + lm) * 136 + k0 + lkb];
    short8 a1 = *(const short8*)&As[(mbase + 16 + lm) * 136 + k0 + lkb];
#pragma unroll
    for (int n = 0; n < 8; n++) {
      short8 b = *(const short8*)&Bs[(n * 16 + lm) * 136 + k0 + lkb];
      acc[0][n] = __builtin_amdgcn_mfma_f32_16x16x32_bf16(a0, b, acc[0][n], 0, 0, 0);
      acc[1][n] = __builtin_amdgcn_mfma_f32_16x16x32_bf16(a1, b, acc[1][n], 0, 0, 0);
    }
  }

  // epilogue: acc -> bf16 in LDS (reuse As), then coalesced copy-out
  __syncthreads();
  const int rquad = (lane >> 4) * 4;
#pragma unroll
  for (int t = 0; t < 2; t++)
#pragma unroll
    for (int i = 0; i < 4; i++) {
      int lrow = mbase + t * 16 + rquad + i;
#pragma unroll
      for (int n = 0; n < 8; n++)
        As[lrow * 136 + n * 16 + lm] = f2b(acc[t][n][i]);
    }
  __syncthreads();
#pragma unroll
  for (int i = 0; i < 8; i++) {
    int seg = tid + i * 256;
    int row = seg >> 4, c8 = (seg & 15) * 8;
    int gr = m0 + row;
    if (gr < NN)
      *(uint4*)&C[(size_t)gr * DD + c8] = *(const uint4*)&As[row * 136 + c8];
  }
}

// ---------- gathers ----------

// layer-1: block = 2 nodes x 4 groups x 32 lanes; group g handles rels 2g,2g+1.
// A2[v][c] = bf16(relu(sum_r sum_bucket scale * Hall[r][src][c]))
__global__ __launch_bounds__(256) void gather1_kernel(const int* __restrict__ off,
                                                      const uint2* __restrict__ rec,
                                                      const ushort* __restrict__ Hall,
                                                      ushort* __restrict__ A2) {
  __shared__ float part[2][4][128];
  const int tid = threadIdx.x;
  const int nloc = tid >> 7;
  const int v = blockIdx.x * 2 + nloc;
  const int g = (tid >> 5) & 3;
  const int l = tid & 31;
  const int c4 = l * 4;
  float a0 = 0.f, a1 = 0.f, a2 = 0.f, a3 = 0.f;
#pragma unroll
  for (int rr = 0; rr < 2; rr++) {
    int r = g * 2 + rr;
    int b = r * NN + v;
    int s = off[b], e = off[b + 1];
    const ushort* Hr = Hall + (size_t)r * NN * DD;
    for (int i = s; i < e; i++) {
      uint2 q = rec[i];
      float sc = __uint_as_float(q.y);
      ushort4 h = *(const ushort4*)&Hr[(size_t)q.x * DD + c4];
      a0 = fmaf(sc, bf2f(h.x), a0);
      a1 = fmaf(sc, bf2f(h.y), a1);
      a2 = fmaf(sc, bf2f(h.z), a2);
      a3 = fmaf(sc, bf2f(h.w), a3);
    }
  }
  *(float4*)&part[nloc][g][c4] = make_float4(a0, a1, a2, a3);
  __syncthreads();
  if (g == 0) {
    float4 p0 = *(const float4*)&part[nloc][0][c4];
    float4 p1 = *(const float4*)&part[nloc][1][c4];
    float4 p2 = *(const float4*)&part[nloc][2][c4];
    float4 p3 = *(const float4*)&part[nloc][3][c4];
    float s0 = fmaxf(p0.x + p1.x + p2.x + p3.x, 0.f);
    float s1 = fmaxf(p0.y + p1.y + p2.y + p3.y, 0.f);
    float s2 = fmaxf(p0.z + p1.z + p2.z + p3.z, 0.f);
    float s3 = fmaxf(p0.w + p1.w + p2.w + p3.w, 0.f);
    *(ushort4*)&A2[(size_t)v * DD + c4] = make_ushort4(f2b(s0), f2b(s1), f2b(s2), f2b(s3));
  }
}

// layer-2 + log_softmax: block = 2 nodes x 8 rel-groups x 16 lanes
__global__ __launch_bounds__(256) void gather2_kernel(const int* __restrict__ off,
                                                      const uint2* __restrict__ rec,
                                                      const ushort* __restrict__ H2,
                                                      float* __restrict__ out) {
  __shared__ float part[2][8][16];
  const int tid = threadIdx.x;
  const int nloc = tid >> 7;
  const int v = blockIdx.x * 2 + nloc;
  const int r = (tid >> 4) & 7;
  const int c = tid & 15;
  int b = r * NN + v;
  int s = off[b], e = off[b + 1];
  float acc = 0.f;
  for (int i = s; i < e; i++) {
    uint2 q = rec[i];
    acc = fmaf(__uint_as_float(q.y), bf2f(H2[(size_t)q.x * DD + r * NCLS + c]), acc);
  }
  part[nloc][r][c] = acc;
  __syncthreads();
  if (r == 0) {
    float val = 0.f;
#pragma unroll
    for (int g = 0; g < 8; g++) val += part[nloc][g][c];
    float m = val;
#pragma unroll
    for (int mask = 8; mask >= 1; mask >>= 1) m = fmaxf(m, __shfl_xor(m, mask, 16));
    float ex = expf(val - m);
#pragma unroll
    for (int mask = 8; mask >= 1; mask >>= 1) ex += __shfl_xor(ex, mask, 16);
    out[(size_t)v * NCLS + c] = val - m - logf(ex);
  }
}

extern "C" void kernel_launch(void* const* d_in, const int* in_sizes, int n_in,
                              void* d_out, int out_size, void* d_ws, size_t ws_size,
                              hipStream_t stream) {
  const float* x  = (const float*)d_in[0];
  const int*   ei = (const int*)d_in[1];
  const int*   et = (const int*)d_in[2];
  const float* ew = (const float*)d_in[3];
  const float* W1 = (const float*)d_in[4];
  const float* W2 = (const float*)d_in[5];
  float* out = (float*)d_out;
  float* ws = (float*)d_ws;

  // workspace layout (float-unit offsets; ~138 MB of 256 MB)
  float*  cnt    = ws;                         // 400000
  int*    off    = (int*)(ws + 400000);        // 400001
  int*    bsum   = (int*)(ws + 800004);        // 1563
  int*    bpre   = (int*)(ws + 801568);        // 1563
  int*    cursor = (int*)(ws + 803132);        // 400000
  uint2*  rec    = (uint2*)(ws + 1203132);     // 640000 uint2
  ushort* xb     = (ushort*)(ws + 2483132);    // NN*DD bf16
  ushort* W1T    = (ushort*)(ws + 5683132);    // 8*128*128 bf16
  ushort* W2T    = (ushort*)(ws + 5748668);    // 128*128 bf16
  ushort* A2     = (ushort*)(ws + 5756860);    // NN*DD bf16
  ushort* H_all  = (ushort*)(ws + 8956860);    // 8 * NN*DD bf16
  ushort* H2     = H_all;                      // reuse slot 0 after gather1

  hipMemsetAsync(cnt, 0, (size_t)NBUCK * sizeof(float), stream);

  count_kernel<<<(EE + 255) / 256, 256, 0, stream>>>(ei, et, cnt);
  scan1_kernel<<<SCAN_NB, 256, 0, stream>>>(cnt, off, bsum);
  scan2_kernel<<<1, 256, 0, stream>>>(bsum, bpre);
  scan3_kernel<<<SCAN_NB, 256, 0, stream>>>(off, bpre);
  hipMemcpyAsync(cursor, off, (size_t)NBUCK * sizeof(int), hipMemcpyDeviceToDevice, stream);
  bucket_kernel<<<(EE + 255) / 256, 256, 0, stream>>>(ei, et, ew, cnt, cursor, rec);

  pack_x_kernel<<<(NN * DD / 4 + 255) / 256, 256, 0, stream>>>(x, xb);
  pack_w_kernel<<<(NREL * DD * DD + DD * DD + 255) / 256, 256, 0, stream>>>(W1, W2, W1T, W2T);

  // layer 1: all 8 relation GEMMs in one dispatch
  dim3 g1((NN + 127) / 128, NREL);
  mfma_gemm_kernel<<<g1, 256, 0, stream>>>(xb, W1T, DD * DD, H_all, (long)NN * DD);
  gather1_kernel<<<NN / 2, 256, 0, stream>>>(off, rec, H_all, A2);

  // layer 2: one GEMM (8 relations' 128x16 concatenated), then gather + lsm
  dim3 g2((NN + 127) / 128, 1);
  mfma_gemm_kernel<<<g2, 256, 0, stream>>>(A2, W2T, 0, H2, 0);
  gather2_kernel<<<NN / 2, 256, 0, stream>>>(off, rec, H2, out);
}